// Round 12
// baseline (1250.197 us; speedup 1.0000x reference)
//
#include <hip/hip_runtime.h>
#include <hip/hip_fp16.h>

#define N_NODES 100000
#define N_EDGES 1600000
#define D 128
#define NBKT 391        // ceil(100000/256) buckets of 256 dst nodes
#define BKT_CAP 5120    // mean bucket size 4096, sigma~64 -> 16-sigma margin
#define NB_GEMM 782     // ceil(100000/128) 128-row MFMA blocks
#define NB_BINA 782     // ceil((1600000/4)/512) edge-quad blocks
#define NSLICE 8        // channel slices; slice = blockIdx&7 -> XCD pinning
#define SCH 16          // channels per slice (32 B fp16); slice array = 3.2 MB (L2-fits)

typedef _Float16 f16x8 __attribute__((ext_vector_type(8)));
typedef float f32x4 __attribute__((ext_vector_type(4)));

// XOR-swizzle for 256B-row-stride LDS tiles (see R7): b128 column reads across
// 16 rows spread over 8 bank groups.
#define SWZ(b) ((b) ^ ((((b) >> 8) & 7) << 4))

// ==================== mega kernel: MFMA gemm1 blocks || binA blocks ====================
// gemm1: q = fp16(feature @ W1), unscaled, written in SLICED layout:
//        q[slice][node][16ch]. 512 thr = 8 waves x 16 rows = 128 rows/block.
// binA : bin edges by dst>>8 into bucket regions as (src<<8|dst_local) records.

__global__ __launch_bounds__(512) void mega_kernel(const float* __restrict__ x,
                                                   const float* __restrict__ W,
                                                   _Float16* __restrict__ q,
                                                   const int* __restrict__ src,
                                                   const int* __restrict__ dst,
                                                   int* __restrict__ gcnt,
                                                   int* __restrict__ staged) {
    __shared__ __align__(16) char smem[32768];
    const int tid = threadIdx.x;
    const int bid = blockIdx.x;

    if (bid < NB_GEMM) {
        // ---- MFMA gemm1 path (validated R9: absmax 9.8e-4) ----
        const int lane = tid & 63;
        const int w = tid >> 6;        // wave 0..7 -> 16-row strip
        const int r16 = lane & 15;     // A-row / B-col / D-col within tile
        const int g = lane >> 4;       // k-group: k = g*8 + j
        const int row0 = bid * 128;
        const int row = row0 + w * 16 + r16;
        const int rowc = row < N_NODES ? row : N_NODES - 1;  // clamp loads, guard stores
        const float* xp = x + (size_t)rowc * D;
        f16x8 a[4];
#pragma unroll
        for (int kt = 0; kt < 4; ++kt) {
            const float4 lo = *(const float4*)(xp + kt * 32 + g * 8);
            const float4 hi = *(const float4*)(xp + kt * 32 + g * 8 + 4);
            f16x8 v;
            v[0] = (_Float16)lo.x; v[1] = (_Float16)lo.y; v[2] = (_Float16)lo.z; v[3] = (_Float16)lo.w;
            v[4] = (_Float16)hi.x; v[5] = (_Float16)hi.y; v[6] = (_Float16)hi.z; v[7] = (_Float16)hi.w;
            a[kt] = v;
        }
        // Wt into LDS: fp16, transposed (Wt[n][k]), swizzled.
        {
            const int n = tid & 127;
            const int k0 = (tid >> 7) * 32;
#pragma unroll
            for (int c = 0; c < 4; ++c) {
                f16x8 v;
#pragma unroll
                for (int j = 0; j < 8; ++j) v[j] = (_Float16)W[(k0 + c * 8 + j) * D + n];
                const int byte = n * 256 + (k0 + c * 8) * 2;
                *(f16x8*)(smem + SWZ(byte)) = v;
            }
        }
        __syncthreads();
        f32x4 acc[8];
#pragma unroll
        for (int nt = 0; nt < 8; ++nt) {
            f32x4 c = {0.f, 0.f, 0.f, 0.f};
#pragma unroll
            for (int kt = 0; kt < 4; ++kt) {
                const int byte = (nt * 16 + r16) * 256 + kt * 64 + g * 16;
                const f16x8 b = *(const f16x8*)(smem + SWZ(byte));
                c = __builtin_amdgcn_mfma_f32_16x16x32_f16(a[kt], b, c, 0, 0, 0);
            }
            acc[nt] = c;
        }
        __syncthreads();  // reuse smem as q staging
        // D mapping (m89-verified): D[(lane>>4)*4 + r][lane&15]
        _Float16* qs = (_Float16*)smem;  // [128 rows][128 cols] linear
#pragma unroll
        for (int nt = 0; nt < 8; ++nt)
#pragma unroll
            for (int r = 0; r < 4; ++r)
                qs[(w * 16 + g * 4 + r) * D + nt * 16 + r16] = (_Float16)acc[nt][r];
        __syncthreads();
        // cooperative write: 16B chunk k of row -> slice k>>1, half k&1
        uint4* qg = (uint4*)q;
#pragma unroll
        for (int i = 0; i < 4; ++i) {
            const int c16 = tid + i * 512;       // 0..2047
            const int grow = row0 + (c16 >> 4);
            const int k = c16 & 15;
            if (grow < N_NODES)
                qg[(size_t)(k >> 1) * (N_NODES * 2) + (size_t)grow * 2 + (k & 1)] =
                    *(const uint4*)(smem + c16 * 16);
        }
    } else {
        // ---- binA path: LDS ranks + one global atomicAdd per (block,bucket) ----
        int* hist = (int*)smem;
        if (tid < NBKT) hist[tid] = 0;
        __syncthreads();
        const int i4 = (bid - NB_GEMM) * 512 + tid;
        const bool valid = i4 < N_EDGES / 4;
        int4 dv, sv;
        int lb0 = 0, lb1 = 0, lb2 = 0, lb3 = 0, lr0 = 0, lr1 = 0, lr2 = 0, lr3 = 0;
        if (valid) {
            dv = ((const int4*)dst)[i4];
            sv = ((const int4*)src)[i4];
            lb0 = dv.x >> 8; lr0 = atomicAdd(&hist[lb0], 1);
            lb1 = dv.y >> 8; lr1 = atomicAdd(&hist[lb1], 1);
            lb2 = dv.z >> 8; lr2 = atomicAdd(&hist[lb2], 1);
            lb3 = dv.w >> 8; lr3 = atomicAdd(&hist[lb3], 1);
        }
        __syncthreads();
        if (tid < NBKT) {
            const int c = hist[tid];
            hist[tid] = c ? atomicAdd(&gcnt[tid], c) : 0;
        }
        __syncthreads();
        if (valid) {
            staged[lb0 * BKT_CAP + hist[lb0] + lr0] = (sv.x << 8) | (dv.x & 255);
            staged[lb1 * BKT_CAP + hist[lb1] + lr1] = (sv.y << 8) | (dv.y & 255);
            staged[lb2 * BKT_CAP + hist[lb2] + lr2] = (sv.z << 8) | (dv.z & 255);
            staged[lb3 * BKT_CAP + hist[lb3] + lr3] = (sv.w << 8) | (dv.w & 255);
        }
    }
}

// ==================== dinvB: per-bucket degree -> dinv ====================

__global__ __launch_bounds__(256) void dinvB_kernel(const int* __restrict__ gcnt,
                                                    const int* __restrict__ staged,
                                                    float* __restrict__ dinv) {
    __shared__ int hist[256];
    const int t = threadIdx.x;
    const int b = blockIdx.x;
    hist[t] = 0;
    __syncthreads();
    const int m = gcnt[b];
    const int* reg = staged + (size_t)b * BKT_CAP;
    for (int i = t; i < m; i += 256) atomicAdd(&hist[reg[i] & 255], 1);
    __syncthreads();
    const int node = b * 256 + t;
    if (node < N_NODES) dinv[node] = rsqrtf((float)hist[t] + 1.0f);  // +1 = self-loop
}

// ==================== gatherA: layer-1 aggregate + relu + W2-slice partial dot ====================
// Grid = NBKT*8; slice = blockIdx&7 (-> XCD i%8 under round-robin dispatch), bucket = blockIdx>>3.
// Per XCD the q-slice (3.2 MB) is L2-resident. LDS acc[c][dl]: bank = dl&31, conflict-free.

__global__ __launch_bounds__(256) void gatherA_kernel(const int* __restrict__ gcnt,
                                                      const int* __restrict__ staged,
                                                      const float* __restrict__ dinv,
                                                      const _Float16* __restrict__ q,
                                                      const float* __restrict__ b1,
                                                      const float* __restrict__ W2,
                                                      float* __restrict__ y4) {
    __shared__ float acc[SCH][256];  // 16 KB
    const int t = threadIdx.x;
    const int slice = blockIdx.x & 7;
    const int bucket = blockIdx.x >> 3;
    float4* accv = (float4*)acc;
#pragma unroll
    for (int i = 0; i < 4; ++i) accv[t + i * 256] = float4{0.f, 0.f, 0.f, 0.f};
    __syncthreads();
    const int m = gcnt[bucket];
    const int* reg = staged + (size_t)bucket * BKT_CAP;
    const uint4* qs = (const uint4*)q + (size_t)slice * (N_NODES * 2);
    union U { uint4 u; __half2 h2[4]; };
    for (int i = t; i < m; i += 256) {
        const int rec = reg[i];
        const int s = rec >> 8;
        const int dl = rec & 255;
        const float ds = dinv[s];
        U a, b;
        a.u = qs[(size_t)s * 2];
        b.u = qs[(size_t)s * 2 + 1];
#pragma unroll
        for (int k = 0; k < 4; ++k) {
            const float2 f = __half22float2(a.h2[k]);
            atomicAdd(&acc[2 * k + 0][dl], f.x * ds);
            atomicAdd(&acc[2 * k + 1][dl], f.y * ds);
        }
#pragma unroll
        for (int k = 0; k < 4; ++k) {
            const float2 f = __half22float2(b.h2[k]);
            atomicAdd(&acc[8 + 2 * k + 0][dl], f.x * ds);
            atomicAdd(&acc[8 + 2 * k + 1][dl], f.y * ds);
        }
    }
    __syncthreads();
    const int node = bucket * 256 + t;
    if (node < N_NODES) {
        const float dn = dinv[node];
        U a, b;
        a.u = qs[(size_t)node * 2];
        b.u = qs[(size_t)node * 2 + 1];
        float h[SCH];
#pragma unroll
        for (int k = 0; k < 4; ++k) {
            const float2 f = __half22float2(a.h2[k]);
            h[2 * k + 0] = acc[2 * k + 0][t] + f.x * dn;
            h[2 * k + 1] = acc[2 * k + 1][t] + f.y * dn;
            const float2 g = __half22float2(b.h2[k]);
            h[8 + 2 * k + 0] = acc[8 + 2 * k + 0][t] + g.x * dn;
            h[8 + 2 * k + 1] = acc[8 + 2 * k + 1][t] + g.y * dn;
        }
        const int c0 = slice * SCH;
        float a0 = 0.f, a1 = 0.f, a2 = 0.f;
#pragma unroll
        for (int c = 0; c < SCH; ++c) {
            const float hc = fmaxf(h[c] * dn + b1[c0 + c], 0.f);
            a0 += hc * W2[(c0 + c) * 3 + 0];
            a1 += hc * W2[(c0 + c) * 3 + 1];
            a2 += hc * W2[(c0 + c) * 3 + 2];
        }
        // FIX (R10 bug): store the PRE-SCALED form y4[n] = xw2[n] * dinv[n],
        // which scat2's formula out=(sum y_s + y_n)*dinv_n + b2 requires.
        atomicAdd(&y4[node * 4 + 0], a0 * dn);
        atomicAdd(&y4[node * 4 + 1], a1 * dn);
        atomicAdd(&y4[node * 4 + 2], a2 * dn);
    }
}

// ==================== scat2: layer-2 aggregate via bucket records + LDS acc ====================
// y4[n] = xw2[n]*dinv[n] (padded to 16 B). out = (sum_s y_s + y_n)*dinv_n + b2.

__global__ __launch_bounds__(256) void scat2_kernel(const int* __restrict__ gcnt,
                                                    const int* __restrict__ staged,
                                                    const float* __restrict__ dinv,
                                                    const float* __restrict__ y4,
                                                    const float* __restrict__ b2,
                                                    float* __restrict__ out) {
    __shared__ float a3[3][256];  // 3 KB, bank = dl&31
    const int t = threadIdx.x;
    const int b = blockIdx.x;
    a3[0][t] = 0.f; a3[1][t] = 0.f; a3[2][t] = 0.f;
    __syncthreads();
    const int m = gcnt[b];
    const int* reg = staged + (size_t)b * BKT_CAP;
    for (int i = t; i < m; i += 256) {
        const int rec = reg[i];
        const int s = rec >> 8;
        const int dl = rec & 255;
        const float4 ys = *(const float4*)&y4[(size_t)s * 4];  // 1.6 MB, L2-resident
        atomicAdd(&a3[0][dl], ys.x);
        atomicAdd(&a3[1][dl], ys.y);
        atomicAdd(&a3[2][dl], ys.z);
    }
    __syncthreads();
    const int node = b * 256 + t;
    if (node < N_NODES) {
        const float dn = dinv[node];
        const float4 yn = *(const float4*)&y4[(size_t)node * 4];
        out[node * 3 + 0] = (a3[0][t] + yn.x) * dn + b2[0];
        out[node * 3 + 1] = (a3[1][t] + yn.y) * dn + b2[1];
        out[node * 3 + 2] = (a3[2][t] + yn.z) * dn + b2[2];
    }
}

// ==================== launch ====================

extern "C" void kernel_launch(void* const* d_in, const int* in_sizes, int n_in,
                              void* d_out, int out_size, void* d_ws, size_t ws_size,
                              hipStream_t stream) {
    const float* feature = (const float*)d_in[0];
    const int* edge_index = (const int*)d_in[1];
    const int* src = edge_index;             // edge_index[0, :]
    const int* dst = edge_index + N_EDGES;   // edge_index[1, :]
    const float* W1 = (const float*)d_in[3];
    const float* b1 = (const float*)d_in[4];
    const float* W2 = (const float*)d_in[5];
    const float* b2 = (const float*)d_in[6];
    float* out = (float*)d_out;

    const size_t ND = (size_t)N_NODES * D;
    _Float16* q  = (_Float16*)d_ws;                  // 25.6 MB fp16, SLICED layout
    float* y4    = (float*)(q + ND);                 // 1.6 MB (N*4, .w unused)
    int*   gcnt  = (int*)(y4 + (size_t)N_NODES * 4); // 1.6 KB (contiguous w/ y4 for one memset)
    float* dinv  = (float*)(gcnt + NBKT);            // 0.4 MB
    int*   staged = (int*)(dinv + N_NODES);          // 8.0 MB

    // zero y4 (gatherA atomics) + gcnt (binA) in one shot
    hipMemsetAsync(y4, 0, ((size_t)N_NODES * 4 + NBKT) * sizeof(float), stream);
    mega_kernel<<<NB_GEMM + NB_BINA, 512, 0, stream>>>(feature, W1, q, src, dst, gcnt, staged);
    dinvB_kernel<<<NBKT, 256, 0, stream>>>(gcnt, staged, dinv);
    gatherA_kernel<<<NBKT * NSLICE, 256, 0, stream>>>(gcnt, staged, dinv, q, b1, W2, y4);
    scat2_kernel<<<NBKT, 256, 0, stream>>>(gcnt, staged, dinv, y4, b2, out);
}

// Round 13
// 318.310 us; speedup vs baseline: 3.9276x; 3.9276x over previous
//
#include <hip/hip_runtime.h>
#include <hip/hip_fp16.h>

#define N_NODES 100000
#define N_EDGES 1600000
#define D 128
#define NBKT 391        // ceil(100000/256) buckets of 256 dst nodes
#define BKT_CAP 5120    // mean bucket size 4096, sigma~64 -> 16-sigma margin
#define NB_GEMM 782     // ceil(100000/128) 128-row MFMA blocks
#define NB_BINA 782     // ceil((1600000/4)/512) edge-quad blocks
#define NB_GS 782       // ceil(100000/128) node-blocks for sliced gather

typedef _Float16 f16x8 __attribute__((ext_vector_type(8)));
typedef float f32x4 __attribute__((ext_vector_type(4)));

// XOR-swizzle for 256B-row-stride LDS tiles (see R7).
#define SWZ(b) ((b) ^ ((((b) >> 8) & 7) << 4))

// ==================== mega kernel: MFMA gemm1 blocks || binA blocks ====================
// gemm1: q = fp16(feature @ W1), unscaled, SLICED layout q[slice][node][16ch]
//        (validated R12: absmax 9.8e-4 through this layout).
// binA : bin edges by dst>>8 into bucket regions as (src<<8|dst_local) records.

__global__ __launch_bounds__(512) void mega_kernel(const float* __restrict__ x,
                                                   const float* __restrict__ W,
                                                   _Float16* __restrict__ q,
                                                   const int* __restrict__ src,
                                                   const int* __restrict__ dst,
                                                   int* __restrict__ gcnt,
                                                   int* __restrict__ staged) {
    __shared__ __align__(16) char smem[32768];
    const int tid = threadIdx.x;
    const int bid = blockIdx.x;

    if (bid < NB_GEMM) {
        // ---- MFMA gemm1 path ----
        const int lane = tid & 63;
        const int w = tid >> 6;        // wave 0..7 -> 16-row strip
        const int r16 = lane & 15;     // A-row / B-col / D-col within tile
        const int g = lane >> 4;       // k-group: k = g*8 + j
        const int row0 = bid * 128;
        const int row = row0 + w * 16 + r16;
        const int rowc = row < N_NODES ? row : N_NODES - 1;  // clamp loads, guard stores
        const float* xp = x + (size_t)rowc * D;
        f16x8 a[4];
#pragma unroll
        for (int kt = 0; kt < 4; ++kt) {
            const float4 lo = *(const float4*)(xp + kt * 32 + g * 8);
            const float4 hi = *(const float4*)(xp + kt * 32 + g * 8 + 4);
            f16x8 v;
            v[0] = (_Float16)lo.x; v[1] = (_Float16)lo.y; v[2] = (_Float16)lo.z; v[3] = (_Float16)lo.w;
            v[4] = (_Float16)hi.x; v[5] = (_Float16)hi.y; v[6] = (_Float16)hi.z; v[7] = (_Float16)hi.w;
            a[kt] = v;
        }
        // Wt into LDS: fp16, transposed (Wt[n][k]), swizzled.
        {
            const int n = tid & 127;
            const int k0 = (tid >> 7) * 32;
#pragma unroll
            for (int c = 0; c < 4; ++c) {
                f16x8 v;
#pragma unroll
                for (int j = 0; j < 8; ++j) v[j] = (_Float16)W[(k0 + c * 8 + j) * D + n];
                const int byte = n * 256 + (k0 + c * 8) * 2;
                *(f16x8*)(smem + SWZ(byte)) = v;
            }
        }
        __syncthreads();
        f32x4 acc[8];
#pragma unroll
        for (int nt = 0; nt < 8; ++nt) {
            f32x4 c = {0.f, 0.f, 0.f, 0.f};
#pragma unroll
            for (int kt = 0; kt < 4; ++kt) {
                const int byte = (nt * 16 + r16) * 256 + kt * 64 + g * 16;
                const f16x8 b = *(const f16x8*)(smem + SWZ(byte));
                c = __builtin_amdgcn_mfma_f32_16x16x32_f16(a[kt], b, c, 0, 0, 0);
            }
            acc[nt] = c;
        }
        __syncthreads();  // reuse smem as q staging
        // D mapping (m89-verified): D[(lane>>4)*4 + r][lane&15]
        _Float16* qs = (_Float16*)smem;  // [128 rows][128 cols] linear
#pragma unroll
        for (int nt = 0; nt < 8; ++nt)
#pragma unroll
            for (int r = 0; r < 4; ++r)
                qs[(w * 16 + g * 4 + r) * D + nt * 16 + r16] = (_Float16)acc[nt][r];
        __syncthreads();
        // cooperative write: 16B chunk k of row -> slice k>>1, half k&1
        uint4* qg = (uint4*)q;
#pragma unroll
        for (int i = 0; i < 4; ++i) {
            const int c16 = tid + i * 512;       // 0..2047
            const int grow = row0 + (c16 >> 4);
            const int k = c16 & 15;
            if (grow < N_NODES)
                qg[(size_t)(k >> 1) * (N_NODES * 2) + (size_t)grow * 2 + (k & 1)] =
                    *(const uint4*)(smem + c16 * 16);
        }
    } else {
        // ---- binA path: LDS ranks + one global atomicAdd per (block,bucket) ----
        int* hist = (int*)smem;
        if (tid < NBKT) hist[tid] = 0;
        __syncthreads();
        const int i4 = (bid - NB_GEMM) * 512 + tid;
        const bool valid = i4 < N_EDGES / 4;
        int4 dv, sv;
        int lb0 = 0, lb1 = 0, lb2 = 0, lb3 = 0, lr0 = 0, lr1 = 0, lr2 = 0, lr3 = 0;
        if (valid) {
            dv = ((const int4*)dst)[i4];
            sv = ((const int4*)src)[i4];
            lb0 = dv.x >> 8; lr0 = atomicAdd(&hist[lb0], 1);
            lb1 = dv.y >> 8; lr1 = atomicAdd(&hist[lb1], 1);
            lb2 = dv.z >> 8; lr2 = atomicAdd(&hist[lb2], 1);
            lb3 = dv.w >> 8; lr3 = atomicAdd(&hist[lb3], 1);
        }
        __syncthreads();
        if (tid < NBKT) {
            const int c = hist[tid];
            hist[tid] = c ? atomicAdd(&gcnt[tid], c) : 0;
        }
        __syncthreads();
        if (valid) {
            staged[lb0 * BKT_CAP + hist[lb0] + lr0] = (sv.x << 8) | (dv.x & 255);
            staged[lb1 * BKT_CAP + hist[lb1] + lr1] = (sv.y << 8) | (dv.y & 255);
            staged[lb2 * BKT_CAP + hist[lb2] + lr2] = (sv.z << 8) | (dv.z & 255);
            staged[lb3 * BKT_CAP + hist[lb3] + lr3] = (sv.w << 8) | (dv.w & 255);
        }
    }
}

// ==================== binB: per-bucket CSR emit (row_ptr, esrc, dinv) — R9 verbatim ====================

__global__ __launch_bounds__(256) void binB_kernel(const int* __restrict__ gcnt,
                                                   const int* __restrict__ staged,
                                                   int* __restrict__ row_ptr,
                                                   int* __restrict__ esrc,
                                                   float* __restrict__ dinv) {
    __shared__ int red[256];
    __shared__ int hist[256];
    __shared__ int nbase[256];
    __shared__ int nexc[256];
    const int b = blockIdx.x;
    const int t = threadIdx.x;
    const int m = gcnt[b];
    int partial = 0;
    for (int i = t; i < b; i += 256) partial += gcnt[i];
    red[t] = partial;
    __syncthreads();
    for (int off = 128; off; off >>= 1) {
        if (t < off) red[t] += red[t + off];
        __syncthreads();
    }
    const int bbase = red[0];
    hist[t] = 0;
    __syncthreads();
    const int* reg = staged + (size_t)b * BKT_CAP;
    for (int i = t; i < m; i += 256) atomicAdd(&hist[reg[i] & 255], 1);
    __syncthreads();
    const int v = hist[t];
    nbase[t] = v;
    __syncthreads();
    for (int off = 1; off < 256; off <<= 1) {
        int u = (t >= off) ? nbase[t - off] : 0;
        __syncthreads();
        nbase[t] += u;
        __syncthreads();
    }
    nexc[t] = nbase[t] - v;
    const int node = b * 256 + t;
    if (node < N_NODES) {
        row_ptr[node] = bbase + nexc[t];
        dinv[node] = rsqrtf((float)v + 1.0f);  // +1 = self-loop
    }
    if (b == 0 && t == 0) row_ptr[N_NODES] = N_EDGES;
    hist[t] = 0;
    __syncthreads();
    for (int i = t; i < m; i += 256) {
        const int rec = reg[i];
        const int nl = rec & 255;
        const int r = atomicAdd(&hist[nl], 1);
        esrc[bbase + nexc[nl] + r] = rec >> 8;
    }
}

// ==================== gatherS: sliced layer-1 gather + relu + W2 partial dot ====================
// Grid = NB_GS*8. slice = blockIdx&7 (round-robin -> XCD pinning); per XCD the
// 3.2 MB q-slice is L2-resident. 128 nodes/block, 2 lanes/node, 16B loads,
// REGISTER accumulation (no LDS, no LDS atomics — R12 lesson). Per node:
// 3 global atomicAdds of the slice's partial y4 contribution.

__global__ __launch_bounds__(256) void gatherS_kernel(const int* __restrict__ row_ptr,
                                                      const int* __restrict__ esrc,
                                                      const float* __restrict__ dinv,
                                                      const _Float16* __restrict__ q,
                                                      const float* __restrict__ b1,
                                                      const float* __restrict__ W2,
                                                      float* __restrict__ y4) {
    const int t = threadIdx.x;
    const int slice = blockIdx.x & 7;
    const int node = (blockIdx.x >> 3) * 128 + (t >> 1);
    if (node >= N_NODES) return;
    const int p = t & 1;  // half: channels c0..c0+7
    const uint4* qs = (const uint4*)q + (size_t)slice * (N_NODES * 2);
    const int beg = row_ptr[node], end = row_ptr[node + 1];
    float acc[8] = {0, 0, 0, 0, 0, 0, 0, 0};
    union U { uint4 u; __half2 h2[4]; };
    int j = beg;
    for (; j + 1 < end; j += 2) {  // two independent load chains
        const int s0 = esrc[j];
        const int s1 = esrc[j + 1];
        const float d0 = dinv[s0];
        const float d1 = dinv[s1];
        U u0, u1;
        u0.u = qs[(size_t)s0 * 2 + p];
        u1.u = qs[(size_t)s1 * 2 + p];
#pragma unroll
        for (int k = 0; k < 4; ++k) {
            const float2 f0 = __half22float2(u0.h2[k]);
            const float2 f1 = __half22float2(u1.h2[k]);
            acc[2 * k + 0] += f0.x * d0 + f1.x * d1;
            acc[2 * k + 1] += f0.y * d0 + f1.y * d1;
        }
    }
    if (j < end) {
        const int s = esrc[j];
        const float ds = dinv[s];
        U u0; u0.u = qs[(size_t)s * 2 + p];
#pragma unroll
        for (int k = 0; k < 4; ++k) {
            const float2 f0 = __half22float2(u0.h2[k]);
            acc[2 * k + 0] += f0.x * ds;
            acc[2 * k + 1] += f0.y * ds;
        }
    }
    // self-loop + bias + relu + W2 partial dot over channels c0..c0+7
    const float dn = dinv[node];
    U un; un.u = qs[(size_t)node * 2 + p];
    const int c0 = slice * 16 + p * 8;
    float a0 = 0.f, a1 = 0.f, a2 = 0.f;
#pragma unroll
    for (int k = 0; k < 4; ++k) {
        const float2 fn = __half22float2(un.h2[k]);
        const float h0 = fmaxf((acc[2 * k + 0] + fn.x * dn) * dn + b1[c0 + 2 * k + 0], 0.f);
        const float h1 = fmaxf((acc[2 * k + 1] + fn.y * dn) * dn + b1[c0 + 2 * k + 1], 0.f);
        a0 += h0 * W2[(c0 + 2 * k) * 3 + 0] + h1 * W2[(c0 + 2 * k + 1) * 3 + 0];
        a1 += h0 * W2[(c0 + 2 * k) * 3 + 1] + h1 * W2[(c0 + 2 * k + 1) * 3 + 1];
        a2 += h0 * W2[(c0 + 2 * k) * 3 + 2] + h1 * W2[(c0 + 2 * k + 1) * 3 + 2];
    }
    // combine the 2 lanes of this node, then one atomic per component.
    a0 += __shfl_xor(a0, 1);
    a1 += __shfl_xor(a1, 1);
    a2 += __shfl_xor(a2, 1);
    if (p == 0) {
        // pre-scaled form y4[n] = xw2[n]*dinv[n] (R10 lesson: keep the *dn!)
        atomicAdd(&y4[node * 4 + 0], a0 * dn);
        atomicAdd(&y4[node * 4 + 1], a1 * dn);
        atomicAdd(&y4[node * 4 + 2], a2 * dn);
    }
}

// ==================== gather2: out = (sum_s y_s + y_n) * dinv_n + b2 — R9 verbatim (y4 stride) ====================

__global__ __launch_bounds__(256) void gather2_kernel(const int* __restrict__ row_ptr,
                                                      const int* __restrict__ esrc,
                                                      const float* __restrict__ dinv,
                                                      const float* __restrict__ y4,
                                                      const float* __restrict__ b2,
                                                      float* __restrict__ out) {
    const int t = threadIdx.x;
    const int node = blockIdx.x * 64 + (t >> 2);
    if (node >= N_NODES) return;
    const int sub = t & 3;
    const int beg = row_ptr[node], end = row_ptr[node + 1];
    float a0 = 0.f, a1 = 0.f, a2 = 0.f;
    for (int j = beg + sub; j < end; j += 4) {
        const int s = esrc[j];
        a0 += y4[(size_t)s * 4 + 0];
        a1 += y4[(size_t)s * 4 + 1];
        a2 += y4[(size_t)s * 4 + 2];
    }
    a0 += __shfl_xor(a0, 1); a0 += __shfl_xor(a0, 2);
    a1 += __shfl_xor(a1, 1); a1 += __shfl_xor(a1, 2);
    a2 += __shfl_xor(a2, 1); a2 += __shfl_xor(a2, 2);
    if (sub == 0) {
        const float dn = dinv[node];
        out[node * 3 + 0] = (a0 + y4[(size_t)node * 4 + 0]) * dn + b2[0];
        out[node * 3 + 1] = (a1 + y4[(size_t)node * 4 + 1]) * dn + b2[1];
        out[node * 3 + 2] = (a2 + y4[(size_t)node * 4 + 2]) * dn + b2[2];
    }
}

// ==================== launch ====================

extern "C" void kernel_launch(void* const* d_in, const int* in_sizes, int n_in,
                              void* d_out, int out_size, void* d_ws, size_t ws_size,
                              hipStream_t stream) {
    const float* feature = (const float*)d_in[0];
    const int* edge_index = (const int*)d_in[1];
    const int* src = edge_index;             // edge_index[0, :]
    const int* dst = edge_index + N_EDGES;   // edge_index[1, :]
    const float* W1 = (const float*)d_in[3];
    const float* b1 = (const float*)d_in[4];
    const float* W2 = (const float*)d_in[5];
    const float* b2 = (const float*)d_in[6];
    float* out = (float*)d_out;

    const size_t ND = (size_t)N_NODES * D;
    _Float16* q    = (_Float16*)d_ws;                  // 25.6 MB fp16, SLICED layout
    float* y4      = (float*)(q + ND);                 // 1.6 MB (N*4, .w unused)
    int*   gcnt    = (int*)(y4 + (size_t)N_NODES * 4); // 1.6 KB (contiguous w/ y4: one memset)
    float* dinv    = (float*)(gcnt + NBKT);            // 0.4 MB
    int*   row_ptr = (int*)(dinv + N_NODES);           // 0.4 MB
    int*   esrc    = row_ptr + (N_NODES + 1);          // 6.4 MB
    int*   staged  = esrc + N_EDGES;                   // 8.0 MB

    // zero y4 (gatherS atomics) + gcnt (binA) in one shot
    hipMemsetAsync(y4, 0, ((size_t)N_NODES * 4 + NBKT) * sizeof(float), stream);
    mega_kernel<<<NB_GEMM + NB_BINA, 512, 0, stream>>>(feature, W1, q, src, dst, gcnt, staged);
    binB_kernel<<<NBKT, 256, 0, stream>>>(gcnt, staged, row_ptr, esrc, dinv);
    gatherS_kernel<<<NB_GS * 8, 256, 0, stream>>>(row_ptr, esrc, dinv, q, b1, W2, y4);
    gather2_kernel<<<(N_NODES + 63) / 64, 256, 0, stream>>>(row_ptr, esrc, dinv, y4, b2, out);
}

// Round 14
// 228.709 us; speedup vs baseline: 5.4663x; 1.3918x over previous
//
#include <hip/hip_runtime.h>
#include <hip/hip_fp16.h>

#define N_NODES 100000
#define N_EDGES 1600000
#define D 128
#define NBKT 391        // ceil(100000/256) buckets of 256 dst nodes
#define BKT_CAP 5120    // mean bucket size 4096, sigma~64 -> 16-sigma margin
#define NB_GEMM 782     // ceil(100000/128) 128-row MFMA blocks
#define NB_BINA 782     // ceil((1600000/4)/512) edge-quad blocks

typedef _Float16 f16x8 __attribute__((ext_vector_type(8)));
typedef float f32x4 __attribute__((ext_vector_type(4)));

// XOR-swizzle for 256B-row-stride LDS tiles (see R7).
#define SWZ(b) ((b) ^ ((((b) >> 8) & 7) << 4))

// ==================== binA: bin edges by dst>>8 into bucket regions ====================
// (split out of mega so that BOTH the gemm and binB can start right after it)

__global__ __launch_bounds__(512) void binA_kernel(const int* __restrict__ src,
                                                   const int* __restrict__ dst,
                                                   int* __restrict__ gcnt,
                                                   int* __restrict__ staged) {
    __shared__ int hist[NBKT];
    const int tid = threadIdx.x;
    if (tid < NBKT) hist[tid] = 0;
    __syncthreads();
    const int i4 = blockIdx.x * 512 + tid;
    const bool valid = i4 < N_EDGES / 4;
    int4 dv, sv;
    int lb0 = 0, lb1 = 0, lb2 = 0, lb3 = 0, lr0 = 0, lr1 = 0, lr2 = 0, lr3 = 0;
    if (valid) {
        dv = ((const int4*)dst)[i4];
        sv = ((const int4*)src)[i4];
        lb0 = dv.x >> 8; lr0 = atomicAdd(&hist[lb0], 1);
        lb1 = dv.y >> 8; lr1 = atomicAdd(&hist[lb1], 1);
        lb2 = dv.z >> 8; lr2 = atomicAdd(&hist[lb2], 1);
        lb3 = dv.w >> 8; lr3 = atomicAdd(&hist[lb3], 1);
    }
    __syncthreads();
    if (tid < NBKT) {
        const int c = hist[tid];
        hist[tid] = c ? atomicAdd(&gcnt[tid], c) : 0;
    }
    __syncthreads();
    if (valid) {
        staged[lb0 * BKT_CAP + hist[lb0] + lr0] = (sv.x << 8) | (dv.x & 255);
        staged[lb1 * BKT_CAP + hist[lb1] + lr1] = (sv.y << 8) | (dv.y & 255);
        staged[lb2 * BKT_CAP + hist[lb2] + lr2] = (sv.z << 8) | (dv.z & 255);
        staged[lb3 * BKT_CAP + hist[lb3] + lr3] = (sv.w << 8) | (dv.w & 255);
    }
}

// ==================== fused2: MFMA gemm1 blocks || binB blocks ====================
// Both roles depend only on binA -> they overlap inside one kernel.
// gemm: q = fp16(feature @ W1), NON-sliced layout q[node][128] (R13 lesson:
//       slicing loses; 16-lane/node gather on this layout is the best engine).
// binB: per-bucket CSR emit (row_ptr, esrc, dinv), adapted to 512 threads.

__global__ __launch_bounds__(512) void fused2_kernel(const float* __restrict__ x,
                                                     const float* __restrict__ W,
                                                     _Float16* __restrict__ q,
                                                     const int* __restrict__ gcnt,
                                                     const int* __restrict__ staged,
                                                     int* __restrict__ row_ptr,
                                                     int* __restrict__ esrc,
                                                     float* __restrict__ dinv) {
    __shared__ __align__(16) char smem[32768];
    const int tid = threadIdx.x;
    const int bid = blockIdx.x;

    if (bid < NB_GEMM) {
        // ---- MFMA gemm1 path (R9-validated: absmax 9.8e-4) ----
        const int lane = tid & 63;
        const int w = tid >> 6;        // wave 0..7 -> 16-row strip
        const int r16 = lane & 15;
        const int g = lane >> 4;       // k-group
        const int row0 = bid * 128;
        const int row = row0 + w * 16 + r16;
        const int rowc = row < N_NODES ? row : N_NODES - 1;
        const float* xp = x + (size_t)rowc * D;
        f16x8 a[4];
#pragma unroll
        for (int kt = 0; kt < 4; ++kt) {
            const float4 lo = *(const float4*)(xp + kt * 32 + g * 8);
            const float4 hi = *(const float4*)(xp + kt * 32 + g * 8 + 4);
            f16x8 v;
            v[0] = (_Float16)lo.x; v[1] = (_Float16)lo.y; v[2] = (_Float16)lo.z; v[3] = (_Float16)lo.w;
            v[4] = (_Float16)hi.x; v[5] = (_Float16)hi.y; v[6] = (_Float16)hi.z; v[7] = (_Float16)hi.w;
            a[kt] = v;
        }
        // Wt into LDS: fp16, transposed, swizzled.
        {
            const int n = tid & 127;
            const int k0 = (tid >> 7) * 32;
#pragma unroll
            for (int c = 0; c < 4; ++c) {
                f16x8 v;
#pragma unroll
                for (int j = 0; j < 8; ++j) v[j] = (_Float16)W[(k0 + c * 8 + j) * D + n];
                const int byte = n * 256 + (k0 + c * 8) * 2;
                *(f16x8*)(smem + SWZ(byte)) = v;
            }
        }
        __syncthreads();
        f32x4 acc[8];
#pragma unroll
        for (int nt = 0; nt < 8; ++nt) {
            f32x4 c = {0.f, 0.f, 0.f, 0.f};
#pragma unroll
            for (int kt = 0; kt < 4; ++kt) {
                const int byte = (nt * 16 + r16) * 256 + kt * 64 + g * 16;
                const f16x8 b = *(const f16x8*)(smem + SWZ(byte));
                c = __builtin_amdgcn_mfma_f32_16x16x32_f16(a[kt], b, c, 0, 0, 0);
            }
            acc[nt] = c;
        }
        __syncthreads();  // reuse smem as q staging
        // D mapping (m89-verified): D[(lane>>4)*4 + r][lane&15]
        _Float16* qs = (_Float16*)smem;
#pragma unroll
        for (int nt = 0; nt < 8; ++nt)
#pragma unroll
            for (int r = 0; r < 4; ++r)
                qs[(w * 16 + g * 4 + r) * D + nt * 16 + r16] = (_Float16)acc[nt][r];
        __syncthreads();
        // cooperative coalesced b128 write, NON-sliced q[node][128]
        uint4* qg = (uint4*)q;
#pragma unroll
        for (int i = 0; i < 4; ++i) {
            const int c16 = tid + i * 512;
            const int grow = row0 + (c16 >> 4);
            if (grow < N_NODES)
                qg[(size_t)grow * 16 + (c16 & 15)] = *(const uint4*)(smem + c16 * 16);
        }
    } else {
        // ---- binB path (512-thread adaptation of R9's 256-thread version) ----
        int* red   = (int*)smem;           // [512]
        int* hist  = red + 512;            // [256]
        int* nbase = hist + 256;           // [256]
        int* nexc  = nbase + 256;          // [256]
        const int b = bid - NB_GEMM;
        const int m = gcnt[b];
        int partial = 0;
        for (int i = tid; i < b; i += 512) partial += gcnt[i];
        red[tid] = partial;
        __syncthreads();
        for (int off = 256; off; off >>= 1) {
            if (tid < off) red[tid] += red[tid + off];
            __syncthreads();
        }
        const int bbase = red[0];
        if (tid < 256) hist[tid] = 0;
        __syncthreads();
        const int* reg = staged + (size_t)b * BKT_CAP;
        for (int i = tid; i < m; i += 512) atomicAdd(&hist[reg[i] & 255], 1);
        __syncthreads();
        const int v = (tid < 256) ? hist[tid] : 0;
        if (tid < 256) nbase[tid] = v;
        __syncthreads();
        for (int off = 1; off < 256; off <<= 1) {
            const int u = (tid < 256 && tid >= off) ? nbase[tid - off] : 0;
            __syncthreads();
            if (tid < 256) nbase[tid] += u;
            __syncthreads();
        }
        if (tid < 256) {
            nexc[tid] = nbase[tid] - v;
            const int node = b * 256 + tid;
            if (node < N_NODES) {
                row_ptr[node] = bbase + nexc[tid];
                dinv[node] = rsqrtf((float)v + 1.0f);  // +1 = self-loop
            }
            hist[tid] = 0;  // reuse as per-node cursor
        }
        if (b == 0 && tid == 0) row_ptr[N_NODES] = N_EDGES;
        __syncthreads();
        for (int i = tid; i < m; i += 512) {
            const int rec = reg[i];
            const int nl = rec & 255;
            const int r = atomicAdd(&hist[nl], 1);
            esrc[bbase + nexc[nl] + r] = rec >> 8;
        }
    }
}

// ==================== gather1 + fused gemm2 (R9 verbatim, 65 us measured) ====================
// 16 nodes per 256-thread block; 16 lanes/node, half8 (16B) per lane.

__global__ __launch_bounds__(256) void gather1_kernel(const int* __restrict__ row_ptr,
                                                      const int* __restrict__ esrc,
                                                      const float* __restrict__ dinv,
                                                      const uint4* __restrict__ q4,
                                                      const float* __restrict__ b1,
                                                      const float* __restrict__ W2,
                                                      float* __restrict__ y) {
    const int t = threadIdx.x;
    const int n = blockIdx.x * 16 + (t >> 4);  // N_NODES % 16 == 0
    const int g = t & 15;                      // 8-channel group
    const int beg = row_ptr[n], end = row_ptr[n + 1];
    float acc[8] = {0, 0, 0, 0, 0, 0, 0, 0};
    union U { uint4 u; __half2 h2[4]; };
    int j = beg;
    for (; j + 1 < end; j += 2) {  // two independent 16B load chains
        const int s0 = esrc[j];
        const int s1 = esrc[j + 1];
        const float d0 = dinv[s0];
        const float d1 = dinv[s1];
        U u0, u1;
        u0.u = q4[(size_t)s0 * 16 + g];
        u1.u = q4[(size_t)s1 * 16 + g];
#pragma unroll
        for (int k = 0; k < 4; ++k) {
            const float2 f0 = __half22float2(u0.h2[k]);
            const float2 f1 = __half22float2(u1.h2[k]);
            acc[2 * k + 0] += f0.x * d0 + f1.x * d1;
            acc[2 * k + 1] += f0.y * d0 + f1.y * d1;
        }
    }
    if (j < end) {
        const int s = esrc[j];
        const float ds = dinv[s];
        U u0; u0.u = q4[(size_t)s * 16 + g];
#pragma unroll
        for (int k = 0; k < 4; ++k) {
            const float2 f0 = __half22float2(u0.h2[k]);
            acc[2 * k + 0] += f0.x * ds;
            acc[2 * k + 1] += f0.y * ds;
        }
    }
    // self-loop + bias + relu
    const float dn = dinv[n];
    U un; un.u = q4[(size_t)n * 16 + g];
    const float4 ba = ((const float4*)b1)[g * 2];
    const float4 bb = ((const float4*)b1)[g * 2 + 1];
    float h[8];
#pragma unroll
    for (int k = 0; k < 4; ++k) {
        const float2 fn = __half22float2(un.h2[k]);
        h[2 * k + 0] = acc[2 * k + 0] + fn.x * dn;
        h[2 * k + 1] = acc[2 * k + 1] + fn.y * dn;
    }
    h[0] = fmaxf(h[0] * dn + ba.x, 0.f); h[1] = fmaxf(h[1] * dn + ba.y, 0.f);
    h[2] = fmaxf(h[2] * dn + ba.z, 0.f); h[3] = fmaxf(h[3] * dn + ba.w, 0.f);
    h[4] = fmaxf(h[4] * dn + bb.x, 0.f); h[5] = fmaxf(h[5] * dn + bb.y, 0.f);
    h[6] = fmaxf(h[6] * dn + bb.z, 0.f); h[7] = fmaxf(h[7] * dn + bb.w, 0.f);
    // fused gemm2 over this lane's channels c = 8g..8g+7
    const int c = g * 8;
    float a0 = 0.f, a1 = 0.f, a2 = 0.f;
#pragma unroll
    for (int k = 0; k < 8; ++k) {
        a0 += h[k] * W2[(c + k) * 3 + 0];
        a1 += h[k] * W2[(c + k) * 3 + 1];
        a2 += h[k] * W2[(c + k) * 3 + 2];
    }
#pragma unroll
    for (int off = 8; off; off >>= 1) {  // reduce across the 16-lane group
        a0 += __shfl_xor(a0, off);
        a1 += __shfl_xor(a1, off);
        a2 += __shfl_xor(a2, off);
    }
    if (g == 0) {  // store y[n] = xw2[n] * dinv[n]  (plain store, no memset needed)
        y[n * 3 + 0] = a0 * dn;
        y[n * 3 + 1] = a1 * dn;
        y[n * 3 + 2] = a2 * dn;
    }
}

// ==================== gather2: out = (sum_s y_s + y_n) * dinv_n + b2 (R9 verbatim) ====================

__global__ __launch_bounds__(256) void gather2_kernel(const int* __restrict__ row_ptr,
                                                      const int* __restrict__ esrc,
                                                      const float* __restrict__ dinv,
                                                      const float* __restrict__ y,
                                                      const float* __restrict__ b2,
                                                      float* __restrict__ out) {
    const int t = threadIdx.x;
    const int node = blockIdx.x * 64 + (t >> 2);
    if (node >= N_NODES) return;
    const int sub = t & 3;
    const int beg = row_ptr[node], end = row_ptr[node + 1];
    float a0 = 0.f, a1 = 0.f, a2 = 0.f;
    for (int j = beg + sub; j < end; j += 4) {
        const int s = esrc[j];
        a0 += y[s * 3 + 0];
        a1 += y[s * 3 + 1];
        a2 += y[s * 3 + 2];
    }
    a0 += __shfl_xor(a0, 1); a0 += __shfl_xor(a0, 2);
    a1 += __shfl_xor(a1, 1); a1 += __shfl_xor(a1, 2);
    a2 += __shfl_xor(a2, 1); a2 += __shfl_xor(a2, 2);
    if (sub == 0) {
        const float dn = dinv[node];
        out[node * 3 + 0] = (a0 + y[node * 3 + 0]) * dn + b2[0];
        out[node * 3 + 1] = (a1 + y[node * 3 + 1]) * dn + b2[1];
        out[node * 3 + 2] = (a2 + y[node * 3 + 2]) * dn + b2[2];
    }
}

// ==================== launch ====================

extern "C" void kernel_launch(void* const* d_in, const int* in_sizes, int n_in,
                              void* d_out, int out_size, void* d_ws, size_t ws_size,
                              hipStream_t stream) {
    const float* feature = (const float*)d_in[0];
    const int* edge_index = (const int*)d_in[1];
    const int* src = edge_index;             // edge_index[0, :]
    const int* dst = edge_index + N_EDGES;   // edge_index[1, :]
    const float* W1 = (const float*)d_in[3];
    const float* b1 = (const float*)d_in[4];
    const float* W2 = (const float*)d_in[5];
    const float* b2 = (const float*)d_in[6];
    float* out = (float*)d_out;

    const size_t ND = (size_t)N_NODES * D;
    _Float16* q    = (_Float16*)d_ws;                  // 25.6 MB fp16, q[node][128]
    float* y       = (float*)(q + ND);                 // 1.2 MB
    float* dinv    = y + (size_t)N_NODES * 3;          // 0.4 MB
    int*   row_ptr = (int*)(dinv + N_NODES);           // 0.4 MB
    int*   esrc    = row_ptr + (N_NODES + 1);          // 6.4 MB
    int*   gcnt    = esrc + N_EDGES;                   // 1.6 KB
    int*   staged  = gcnt + NBKT;                      // 8.0 MB

    hipMemsetAsync(gcnt, 0, NBKT * sizeof(int), stream);
    binA_kernel<<<NB_BINA, 512, 0, stream>>>(src, dst, gcnt, staged);
    // gemm (782 blocks) and binB (391 blocks) overlap in one kernel:
    fused2_kernel<<<NB_GEMM + NBKT, 512, 0, stream>>>(feature, W1, q, gcnt, staged,
                                                      row_ptr, esrc, dinv);
    gather1_kernel<<<N_NODES / 16, 256, 0, stream>>>(row_ptr, esrc, dinv, (const uint4*)q, b1, W2, y);
    gather2_kernel<<<(N_NODES + 63) / 64, 256, 0, stream>>>(row_ptr, esrc, dinv, y, b2, out);
}